// Round 2
// baseline (588.312 us; speedup 1.0000x reference)
//
#include <hip/hip_runtime.h>
#include <hip/hip_bf16.h>
#include <math.h>

typedef __bf16 bf16_t;
typedef __bf16 bf16x4 __attribute__((ext_vector_type(4)));
typedef __bf16 bf16x8 __attribute__((ext_vector_type(8)));
typedef float  f32x4  __attribute__((ext_vector_type(4)));

#define NROWS 50000

// monotone float<->uint mapping for atomicMax on floats
__device__ __forceinline__ unsigned int encf(float f) {
    unsigned int u = __float_as_uint(f);
    return (u >> 31) ? ~u : (u | 0x80000000u);
}
__device__ __forceinline__ float decf(unsigned int u) {
    return (u >> 31) ? __uint_as_float(u & 0x7fffffffu) : __uint_as_float(~u);
}

// ---------------- weight permutation ----------------
// permW1[kt 0..31][q 0..3][row 0..511][8] = fcW[row][kt*32+q*8+j]
// permB2[kt 0..15][q 0..3][r 0..527][8]:
//   r<512: interleaved a/b rows; r=512..515: clsW0,clsW1,instW0,instW1 (516..527 garbage, unused)
__global__ void k_convert(const float* __restrict__ fcW,
                          const float* __restrict__ aW,
                          const float* __restrict__ bW,
                          const float* __restrict__ clsW,
                          const float* __restrict__ instW,
                          bf16_t* __restrict__ permW1, bf16_t* __restrict__ permB2,
                          float* __restrict__ sums) {
    int t = blockIdx.x * 256 + threadIdx.x;
    if (t == 0) {
        sums[0] = 0.f; sums[1] = 0.f; sums[2] = 0.f;
        ((unsigned int*)sums)[3] = 0u;          // maxkey = encf(most negative)
    }
    if (t < 131072) {
        float4 v = *(const float4*)(fcW + (long)t * 4);
        int row = t >> 8;
        int k0 = (t & 255) * 4;
        int kt = k0 >> 5, q = (k0 >> 3) & 3, j = k0 & 7;
        bf16_t o[4] = {(bf16_t)v.x, (bf16_t)v.y, (bf16_t)v.z, (bf16_t)v.w};
        *(bf16x4*)(permW1 + kt * 16384 + q * 4096 + row * 8 + j) = *(bf16x4*)o;
    } else if (t < 196608) {
        int t2 = t - 131072;
        int isB = t2 >> 15;
        int f = t2 & 32767;
        float4 v = *(const float4*)(((isB ? bW : aW)) + (long)f * 4);
        int srow = f >> 7;
        int k0 = (f & 127) * 4;
        int kt = k0 >> 5, q = (k0 >> 3) & 3, j = k0 & 7;
        int r = ((srow >> 4) * 2 + isB) * 16 + (srow & 15);
        bf16_t o[4] = {(bf16_t)v.x, (bf16_t)v.y, (bf16_t)v.z, (bf16_t)v.w};
        *(bf16x4*)(permB2 + kt * 16896 + q * 4224 + r * 8 + j) = *(bf16x4*)o;
    } else if (t < 197120) {
        int k = t - 196608;                       // 0..511
        int kt = k >> 5, q = (k >> 3) & 3, j = k & 7;
        bf16_t* base = permB2 + kt * 16896 + q * 4224 + j;
        base[(512 + 0) * 8] = (bf16_t)clsW[k];
        base[(512 + 1) * 8] = (bf16_t)clsW[512 + k];
        base[(512 + 2) * 8] = (bf16_t)instW[k];
        base[(512 + 3) * 8] = (bf16_t)instW[512 + k];
    }
}

// ---------------- fused: GEMM1 -> hh in LDS -> GEMM2 + att + cls + inst ----
// 256 threads = 4 waves (wc 0..3). Block owns 32 rows. 38.4 KB LDS -> 4 blocks/CU.
// Wave tile phase A: 32 rows x 128 cols (acc[2][8]). Phase B: two 256-col passes (acc[2][4]).
__global__ __launch_bounds__(256, 4) void k_fused(
        const float* __restrict__ x,
        const bf16_t* __restrict__ permW1, const bf16_t* __restrict__ permB2,
        const float* __restrict__ fcb,
        const float* __restrict__ aab, const float* __restrict__ abb,
        const float* __restrict__ acW, const float* __restrict__ acb,
        const float* __restrict__ clsb, const float* __restrict__ instb,
        float* __restrict__ Araw, float* __restrict__ inst,
        float* __restrict__ instLog, unsigned int* __restrict__ maxkey) {
    __shared__ __align__(16) char smem[38400];
    // [0,5120): x-stage dbuf 2 x [32 rows][40 elems] bf16 (stride 80 B: 16B-aligned, 2-way banks)
    // [5120,38400): hhT [32][520] bf16 (row stride 1040 B: 16B-aligned, 2-way banks)
    bf16_t* hhT = (bf16_t*)(smem + 5120);

    const int tid = threadIdx.x;
    const int wc = tid >> 6, l = tid & 63, q = l >> 4, li = l & 15;
    const long row0 = (long)blockIdx.x * 32;

    // ================= phase A: hh = relu(x @ W1^T + fcb) =================
    f32x4 acc[2][8];
    #pragma unroll
    for (int a = 0; a < 2; a++)
        #pragma unroll
        for (int c = 0; c < 8; c++) acc[a][c] = (f32x4)0.0f;

    const int srow = tid >> 3;            // 0..31
    const int sk   = (tid & 7) * 4;       // 0,4,..,28
    const bool av  = (row0 + srow) < NROWS;
    const float* xr = x + (row0 + srow) * 1024 + sk;

    float4 xv = av ? *(const float4*)xr : make_float4(0.f, 0.f, 0.f, 0.f);
    {
        bf16_t o[4] = {(bf16_t)xv.x, (bf16_t)xv.y, (bf16_t)xv.z, (bf16_t)xv.w};
        *(bf16x4*)(smem + srow * 80 + sk * 2) = *(bf16x4*)o;
    }
    xv = av ? *(const float4*)(xr + 32) : make_float4(0.f, 0.f, 0.f, 0.f);
    __syncthreads();

    for (int kt = 0; kt < 32; kt++) {
        const int cur = kt & 1;
        if (kt < 31) {
            bf16_t o[4] = {(bf16_t)xv.x, (bf16_t)xv.y, (bf16_t)xv.z, (bf16_t)xv.w};
            *(bf16x4*)(smem + (cur ^ 1) * 2560 + srow * 80 + sk * 2) = *(bf16x4*)o;
            if (kt < 30)
                xv = av ? *(const float4*)(xr + (kt + 2) * 32) : make_float4(0.f, 0.f, 0.f, 0.f);
        }
        const char* As = smem + cur * 2560;
        const bf16_t* Bg = permW1 + kt * 16384 + q * 4096;
        bf16x8 afr[2], bfrA[4], bfrB[4];
        #pragma unroll
        for (int tn = 0; tn < 4; tn++)
            bfrA[tn] = *(const bf16x8*)(Bg + (wc * 128 + tn * 16 + li) * 8);
        #pragma unroll
        for (int tn = 0; tn < 4; tn++)
            bfrB[tn] = *(const bf16x8*)(Bg + (wc * 128 + (tn + 4) * 16 + li) * 8);
        #pragma unroll
        for (int tm = 0; tm < 2; tm++)
            afr[tm] = *(const bf16x8*)(As + (tm * 16 + li) * 80 + q * 16);
        #pragma unroll
        for (int tm = 0; tm < 2; tm++)
            #pragma unroll
            for (int tn = 0; tn < 4; tn++)
                acc[tm][tn] = __builtin_amdgcn_mfma_f32_16x16x32_bf16(afr[tm], bfrA[tn], acc[tm][tn], 0, 0, 0);
        #pragma unroll
        for (int tm = 0; tm < 2; tm++)
            #pragma unroll
            for (int tn = 0; tn < 4; tn++)
                acc[tm][tn + 4] = __builtin_amdgcn_mfma_f32_16x16x32_bf16(afr[tm], bfrB[tn], acc[tm][tn + 4], 0, 0, 0);
        __syncthreads();
    }

    // ---- epilogue A: bias + relu, write hh tile to LDS ----
    #pragma unroll
    for (int tn = 0; tn < 8; tn++) {
        float bias = fcb[wc * 128 + tn * 16 + li];
        #pragma unroll
        for (int tm = 0; tm < 2; tm++)
            #pragma unroll
            for (int r = 0; r < 4; r++) {
                float v = acc[tm][tn][r] + bias;
                v = v > 0.f ? v : 0.f;
                hhT[(tm * 16 + q * 4 + r) * 520 + wc * 128 + tn * 16 + li] = (bf16_t)v;
            }
    }
    __syncthreads();

    // ================= phase B: two 256-col passes over hh @ W2^T, + head tile =========
    float (*apart)[4] = (float (*)[4])smem;          // [32][4] @0    (stage area dead)
    float (*cpart)[4] = (float (*)[4])(smem + 512);  // [32][4] @512

    float sum_mr[2][4];
    #pragma unroll
    for (int a = 0; a < 2; a++)
        #pragma unroll
        for (int c = 0; c < 4; c++) sum_mr[a][c] = 0.f;

    #pragma unroll
    for (int p = 0; p < 2; p++) {
        f32x4 acc2[2][4];
        #pragma unroll
        for (int a = 0; a < 2; a++)
            #pragma unroll
            for (int c = 0; c < 4; c++) acc2[a][c] = (f32x4)0.0f;
        f32x4 ax[2];
        if (p == 0) { ax[0] = (f32x4)0.0f; ax[1] = (f32x4)0.0f; }

        for (int kt = 0; kt < 16; kt++) {
            const bf16_t* Bg = permB2 + kt * 16896 + q * 4224;
            bf16x8 bfr[4], afr2[2];
            #pragma unroll
            for (int tn = 0; tn < 4; tn++)
                bfr[tn] = *(const bf16x8*)(Bg + (p * 256 + wc * 64 + tn * 16 + li) * 8);
            #pragma unroll
            for (int tm = 0; tm < 2; tm++)
                afr2[tm] = *(const bf16x8*)(hhT + (tm * 16 + li) * 520 + kt * 32 + q * 8);
            #pragma unroll
            for (int tm = 0; tm < 2; tm++)
                #pragma unroll
                for (int tn = 0; tn < 4; tn++)
                    acc2[tm][tn] = __builtin_amdgcn_mfma_f32_16x16x32_bf16(afr2[tm], bfr[tn], acc2[tm][tn], 0, 0, 0);
            if (p == 0) {
                bf16x8 bx = *(const bf16x8*)(Bg + (512 + li) * 8);
                #pragma unroll
                for (int tm = 0; tm < 2; tm++)
                    ax[tm] = __builtin_amdgcn_mfma_f32_16x16x32_bf16(afr2[tm], bx, ax[tm], 0, 0, 0);
            }
        }

        // att partials for this pass's 256 cols (a/b interleaved in 16-col groups)
        #pragma unroll
        for (int pp = 0; pp < 2; pp++) {
            int j = (p * 8 + wc * 2 + pp) * 16 + li;   // feature 0..255
            float ab_ = aab[j], bb_ = abb[j], cw = acW[j];
            #pragma unroll
            for (int tm = 0; tm < 2; tm++)
                #pragma unroll
                for (int r = 0; r < 4; r++) {
                    float avv = tanhf(acc2[tm][2 * pp][r] + ab_);
                    float bvv = acc2[tm][2 * pp + 1][r] + bb_;
                    bvv = 1.f / (1.f + expf(-bvv));
                    sum_mr[tm][r] += avv * bvv * cw;
                }
        }
        if (p == 0 && wc == 0 && li < 4) {   // head tile: lane li holds col li (cls0,cls1,inst0,inst1)
            #pragma unroll
            for (int tm = 0; tm < 2; tm++)
                #pragma unroll
                for (int r = 0; r < 4; r++)
                    cpart[tm * 16 + q * 4 + r][li] = ax[tm][r];
        }
    }

    #pragma unroll
    for (int tm = 0; tm < 2; tm++)
        #pragma unroll
        for (int r = 0; r < 4; r++) {
            float v = sum_mr[tm][r];
            v += __shfl_xor(v, 1); v += __shfl_xor(v, 2);
            v += __shfl_xor(v, 4); v += __shfl_xor(v, 8);
            if (li == 0) apart[tm * 16 + q * 4 + r][wc] = v;
        }
    __syncthreads();

    if (tid < 32) {
        long g = row0 + tid;
        float s = apart[tid][0] + apart[tid][1] + apart[tid][2] + apart[tid][3] + acb[0];
        float sv = (g < NROWS) ? s : -3e38f;
        if (g < NROWS) {
            Araw[g] = s;
            inst[g * 2]     = cpart[tid][0] + clsb[0];
            inst[g * 2 + 1] = cpart[tid][1] + clsb[1];
            instLog[g * 2]     = cpart[tid][2] + instb[0];
            instLog[g * 2 + 1] = cpart[tid][3] + instb[1];
        }
        unsigned int key = encf(sv);
        #pragma unroll
        for (int m = 1; m < 32; m <<= 1) {
            unsigned int o = __shfl_xor(key, m);
            key = (o > key) ? o : key;
        }
        if (tid == 0) atomicMax(maxkey, key);
    }
}

// ---------------- merged small pass: blocks 0..7 topk partials, 8..135 softmax sums ----
__global__ void k_part(const float* __restrict__ Araw, const float* __restrict__ inst,
                       float* __restrict__ candV, int* __restrict__ candI,
                       float* __restrict__ sums) {
    __shared__ __align__(16) char sm[32768];
    int tid = threadIdx.x;        // 512
    int b = blockIdx.x;           // 0..135
    if (b < 8) {
        float* cv = (float*)sm;
        int*   ci = (int*)(sm + 16384);
        int pass = b & 1, rq = b >> 1;
        float sign = pass ? -1.f : 1.f;
        int lo = rq * 12500, hi = lo + 12500;
        float tv[8]; int ti[8];
        #pragma unroll
        for (int k = 0; k < 8; k++) { tv[k] = -1e30f; ti[k] = 0x7fffffff; }
        for (int i = lo + tid; i < hi; i += 512) {
            float v = sign * Araw[i];
            if (v > tv[7] || (v == tv[7] && i < ti[7])) {
                int k = 7;
                while (k > 0 && (v > tv[k-1] || (v == tv[k-1] && i < ti[k-1]))) {
                    tv[k] = tv[k-1]; ti[k] = ti[k-1]; k--;
                }
                tv[k] = v; ti[k] = i;
            }
        }
        #pragma unroll
        for (int k = 0; k < 8; k++) { cv[tid * 8 + k] = tv[k]; ci[tid * 8 + k] = ti[k]; }
        __syncthreads();
        if (tid < 64) {
            float mv[8]; int mi[8];
            #pragma unroll
            for (int k = 0; k < 8; k++) { mv[k] = -1e30f; mi[k] = 0x7fffffff; }
            for (int i = 0; i < 64; i++) {
                int slot = tid * 64 + ((i + tid) & 63);
                float v = cv[slot]; int idx = ci[slot];
                #pragma unroll
                for (int k = 0; k < 8; k++) {
                    bool bt = (v > mv[k]) || (v == mv[k] && idx < mi[k]);
                    float nv = bt ? v : mv[k];  int ni = bt ? idx : mi[k];
                    float ov = bt ? mv[k] : v;  int oi = bt ? mi[k] : idx;
                    mv[k] = nv; mi[k] = ni; v = ov; idx = oi;
                }
            }
            for (int r = 0; r < 8; r++) {
                float bv = mv[0]; int bi = mi[0]; int bs = tid;
                for (int m = 1; m < 64; m <<= 1) {
                    float ov = __shfl_xor(bv, m); int oi = __shfl_xor(bi, m); int os = __shfl_xor(bs, m);
                    if (ov > bv || (ov == bv && oi < bi)) { bv = ov; bi = oi; bs = os; }
                }
                if (tid == 0) {
                    candV[pass * 32 + rq * 8 + r] = bv;
                    candI[pass * 32 + rq * 8 + r] = bi;
                }
                if (tid == bs) {
                    #pragma unroll
                    for (int k = 0; k < 7; k++) { mv[k] = mv[k+1]; mi[k] = mi[k+1]; }
                    mv[7] = -1e30f; mi[7] = 0x7fffffff;
                }
            }
        }
    } else {
        float* r0 = (float*)sm;           // [8]
        float* r1 = r0 + 8;
        float* r2 = r0 + 16;
        float mx = decf(((const unsigned int*)sums)[3]);
        int i = (b - 8) * 512 + tid;
        float se = 0.f, s0 = 0.f, s1 = 0.f;
        if (i < NROWS) {
            float e = expf(Araw[i] - mx);
            se = e; s0 = inst[2 * i] * e; s1 = inst[2 * i + 1] * e;
        }
        for (int s = 1; s < 64; s <<= 1) {
            se += __shfl_xor(se, s); s0 += __shfl_xor(s0, s); s1 += __shfl_xor(s1, s);
        }
        int w = tid >> 6;
        if ((tid & 63) == 0) { r0[w] = se; r1[w] = s0; r2[w] = s1; }
        __syncthreads();
        if (tid == 0) {
            float a0 = 0.f, a1 = 0.f, a2 = 0.f;
            #pragma unroll
            for (int k = 0; k < 8; k++) { a0 += r0[k]; a1 += r1[k]; a2 += r2[k]; }
            if (a0 != 0.f || a1 != 0.f || a2 != 0.f) {
                atomicAdd(&sums[0], a0);
                atomicAdd(&sums[1], a1);
                atomicAdd(&sums[2], a2);
            }
        }
    }
}

// ---------------- finalize: merge 32+32 candidates, preds + instance_loss from logits ----
__global__ void k_fin(const float* __restrict__ instLog,
                      const float* __restrict__ candV, const int* __restrict__ candI,
                      const float* __restrict__ sums, float* __restrict__ dout) {
    __shared__ int mid[16];
    int tid = threadIdx.x;          // 128
    int wv = tid >> 6, l = tid & 63;
    if (wv < 2) {
        float v; int idx;
        if (l < 32) { v = candV[wv * 32 + l]; idx = candI[wv * 32 + l]; }
        else        { v = -1e30f; idx = 0x7fffffff; }
        for (int r = 0; r < 8; r++) {
            float bv = v; int bi = idx; int bs = l;
            for (int m = 1; m < 64; m <<= 1) {
                float ov = __shfl_xor(bv, m); int oi = __shfl_xor(bi, m); int os = __shfl_xor(bs, m);
                if (ov > bv || (ov == bv && oi < bi)) { bv = ov; bi = oi; bs = os; }
            }
            if (l == 0) mid[wv * 8 + r] = bi;
            if (l == bs) { v = -1e30f; idx = 0x7fffffff; }
        }
    }
    __syncthreads();
    if (tid < 16) {
        int id = mid[tid];
        float l0 = instLog[id * 2], l1 = instLog[id * 2 + 1];
        float mx = fmaxf(l0, l1);
        float lse = mx + logf(expf(l0 - mx) + expf(l1 - mx));
        float lt = (tid < 8) ? l1 : l0;
        float term = lse - lt;
        for (int m = 1; m < 16; m <<= 1) term += __shfl_xor(term, m);
        if (tid == 0) {
            dout[150002] = term / 16.f;
            float se = sums[0];
            dout[0] = sums[1] / se;
            dout[1] = sums[2] / se;
        }
    }
}

extern "C" void kernel_launch(void* const* d_in, const int* in_sizes, int n_in,
                              void* d_out, int out_size, void* d_ws, size_t ws_size,
                              hipStream_t stream) {
    const float* h   = (const float*)d_in[0];
    const float* fcW = (const float*)d_in[1];
    const float* fcb = (const float*)d_in[2];
    const float* aaW = (const float*)d_in[3];
    const float* aab = (const float*)d_in[4];
    const float* abW = (const float*)d_in[5];
    const float* abb = (const float*)d_in[6];
    const float* acW = (const float*)d_in[7];
    const float* acb = (const float*)d_in[8];
    const float* clW = (const float*)d_in[9];
    const float* clb = (const float*)d_in[10];
    const float* inW = (const float*)d_in[11];
    const float* inb = (const float*)d_in[12];
    float* out = (float*)d_out;

    char* ws = (char*)d_ws;
    bf16_t* permW1  = (bf16_t*)(ws);                       // 1,048,576 B
    bf16_t* permB2  = (bf16_t*)(ws + 1048576);             // 540,672 B
    float*  instLog = (float*) (ws + 1589248);             // 400,000 B
    float*  candV   = (float*) (ws + 1989248);             // 256 B
    int*    candI   = (int*)   (ws + 1989504);             // 256 B
    float*  sums    = (float*) (ws + 1989760);             // 16 B (s0,s1,s2,maxkey)

    float* inst = out + 2;
    float* Araw = out + 2 + 100000;

    k_convert<<<770, 256, 0, stream>>>(fcW, aaW, abW, clW, inW, permW1, permB2, sums);
    k_fused<<<1563, 256, 0, stream>>>(h, permW1, permB2, fcb, aab, abb, acW, acb, clb, inb,
                                      Araw, inst, instLog, (unsigned int*)sums + 3);
    k_part<<<136, 512, 0, stream>>>(Araw, inst, candV, candI, sums);
    k_fin<<<1, 128, 0, stream>>>(instLog, candV, candI, sums, out);
}

// Round 4
// 465.041 us; speedup vs baseline: 1.2651x; 1.2651x over previous
//
#include <hip/hip_runtime.h>
#include <hip/hip_bf16.h>
#include <math.h>

typedef __bf16 bf16_t;
typedef __bf16 bf16x4 __attribute__((ext_vector_type(4)));
typedef __bf16 bf16x8 __attribute__((ext_vector_type(8)));
typedef float  f32x4  __attribute__((ext_vector_type(4)));

#define NROWS 50000

// monotone float<->uint mapping for atomicMax on floats
__device__ __forceinline__ unsigned int encf(float f) {
    unsigned int u = __float_as_uint(f);
    return (u >> 31) ? ~u : (u | 0x80000000u);
}
__device__ __forceinline__ float decf(unsigned int u) {
    return (u >> 31) ? __uint_as_float(u & 0x7fffffffu) : __uint_as_float(~u);
}

// ---------------- weight permutation ----------------
// permW1[kt 0..31][q 0..3][row 0..511][8] = fcW[row][kt*32+q*8+j]
// permB2[kt 0..15][q 0..3][r 0..511][8]   = interleaved a/b rows
__global__ void k_convert(const float* __restrict__ fcW,
                          const float* __restrict__ aW,
                          const float* __restrict__ bW,
                          bf16_t* __restrict__ permW1, bf16_t* __restrict__ permB2,
                          float* __restrict__ sums) {
    int t = blockIdx.x * 256 + threadIdx.x;
    if (t == 0) {
        sums[0] = 0.f; sums[1] = 0.f; sums[2] = 0.f;
        ((unsigned int*)sums)[3] = 0u;          // maxkey = encf(most negative)
    }
    if (t < 131072) {
        float4 v = *(const float4*)(fcW + (long)t * 4);
        int row = t >> 8;
        int k0 = (t & 255) * 4;
        int kt = k0 >> 5, q = (k0 >> 3) & 3, j = k0 & 7;
        bf16_t o[4] = {(bf16_t)v.x, (bf16_t)v.y, (bf16_t)v.z, (bf16_t)v.w};
        *(bf16x4*)(permW1 + kt * 16384 + q * 4096 + row * 8 + j) = *(bf16x4*)o;
    } else if (t < 196608) {
        int t2 = t - 131072;
        int isB = t2 >> 15;
        int f = t2 & 32767;
        float4 v = *(const float4*)(((isB ? bW : aW)) + (long)f * 4);
        int srow = f >> 7;
        int k0 = (f & 127) * 4;
        int kt = k0 >> 5, q = (k0 >> 3) & 3, j = k0 & 7;
        int r = ((srow >> 4) * 2 + isB) * 16 + (srow & 15);
        bf16_t o[4] = {(bf16_t)v.x, (bf16_t)v.y, (bf16_t)v.z, (bf16_t)v.w};
        *(bf16x4*)(permB2 + kt * 16384 + q * 4096 + r * 8 + j) = *(bf16x4*)o;
    }
}

// ---------------- fused: GEMM1 -> hh in LDS -> GEMM2 + att + cls/inst heads ----
// 512 threads = 8 waves, 1x8 layout (wave w owns all 64 rows x cols [w*64, w*64+64)).
// No B-fragment duplication across waves. LDS 76.8 KB -> 2 blocks/CU, 4 waves/SIMD.
// Reg budget: 64 AGPR acc + ~55 arch <= 128 (launch_bounds(512,4) cap).
__global__ __launch_bounds__(512, 4) void k_fused(
        const float* __restrict__ x,
        const bf16_t* __restrict__ permW1, const bf16_t* __restrict__ permB2,
        const float* __restrict__ fcb,
        const float* __restrict__ aab, const float* __restrict__ abb,
        const float* __restrict__ acW, const float* __restrict__ acb,
        const float* __restrict__ clsW, const float* __restrict__ clsb,
        const float* __restrict__ instW, const float* __restrict__ instb,
        float* __restrict__ Araw, float* __restrict__ inst,
        float* __restrict__ instLog, unsigned int* __restrict__ maxkey) {
    __shared__ __align__(16) char smem[76800];
    // [0,10240): x-stage dbuf 2 x [64 rows][40 elems] bf16 (row stride 80 B)
    // [10240,76800): hhT [64][520] bf16 (row stride 1040 B, 2-way banks on b128 col reads)
    bf16_t* hhT = (bf16_t*)(smem + 10240);

    const int tid = threadIdx.x;
    const int w = tid >> 6, l = tid & 63, q = l >> 4, li = l & 15;
    const long row0 = (long)blockIdx.x * 64;

    // ================= phase A: hh = relu(x @ W1^T + fcb) =================
    f32x4 acc[4][4];
    #pragma unroll
    for (int a = 0; a < 4; a++)
        #pragma unroll
        for (int c = 0; c < 4; c++) acc[a][c] = (f32x4)0.0f;

    const int srow = tid >> 3;            // 0..63
    const int sk   = (tid & 7) * 4;       // 0,4,..,28
    const bool av  = (row0 + srow) < NROWS;
    const float* xr = x + (row0 + srow) * 1024 + sk;

    float4 xv = av ? *(const float4*)xr : make_float4(0.f, 0.f, 0.f, 0.f);
    {
        bf16_t o[4] = {(bf16_t)xv.x, (bf16_t)xv.y, (bf16_t)xv.z, (bf16_t)xv.w};
        *(bf16x4*)(smem + srow * 80 + sk * 2) = *(bf16x4*)o;
    }
    xv = av ? *(const float4*)(xr + 32) : make_float4(0.f, 0.f, 0.f, 0.f);
    __syncthreads();

    for (int kt = 0; kt < 32; kt++) {
        const int cur = kt & 1;
        if (kt < 31) {
            bf16_t o[4] = {(bf16_t)xv.x, (bf16_t)xv.y, (bf16_t)xv.z, (bf16_t)xv.w};
            *(bf16x4*)(smem + (cur ^ 1) * 5120 + srow * 80 + sk * 2) = *(bf16x4*)o;
            if (kt < 30)
                xv = av ? *(const float4*)(xr + (kt + 2) * 32) : make_float4(0.f, 0.f, 0.f, 0.f);
        }
        const char* As = smem + cur * 5120;
        const bf16_t* Bg = permW1 + kt * 16384 + q * 4096;
        bf16x8 afr[4];
        #pragma unroll
        for (int tm = 0; tm < 4; tm++)
            afr[tm] = *(const bf16x8*)(As + (tm * 16 + li) * 80 + q * 16);
        #pragma unroll
        for (int tn = 0; tn < 4; tn++) {
            bf16x8 bfr = *(const bf16x8*)(Bg + (w * 64 + tn * 16 + li) * 8);
            #pragma unroll
            for (int tm = 0; tm < 4; tm++)
                acc[tm][tn] = __builtin_amdgcn_mfma_f32_16x16x32_bf16(afr[tm], bfr, acc[tm][tn], 0, 0, 0);
        }
        __syncthreads();
    }

    // ---- epilogue A: bias + relu, write hh tile to LDS ----
    #pragma unroll
    for (int tn = 0; tn < 4; tn++) {
        float bias = fcb[w * 64 + tn * 16 + li];
        #pragma unroll
        for (int tm = 0; tm < 4; tm++)
            #pragma unroll
            for (int r = 0; r < 4; r++) {
                float v = acc[tm][tn][r] + bias;
                v = v > 0.f ? v : 0.f;
                hhT[(tm * 16 + q * 4 + r) * 520 + w * 64 + tn * 16 + li] = (bf16_t)v;
            }
    }
    __syncthreads();

    // ================= phase B: [a|b] = hh @ W2^T, barrier-free =================
    f32x4 acc2[4][4];
    #pragma unroll
    for (int a = 0; a < 4; a++)
        #pragma unroll
        for (int c = 0; c < 4; c++) acc2[a][c] = (f32x4)0.0f;

    for (int kt = 0; kt < 16; kt++) {
        const bf16_t* Bg = permB2 + kt * 16384 + q * 4096;
        bf16x8 afr2[4];
        #pragma unroll
        for (int tm = 0; tm < 4; tm++)
            afr2[tm] = *(const bf16x8*)(hhT + (tm * 16 + li) * 520 + kt * 32 + q * 8);
        #pragma unroll
        for (int tn = 0; tn < 4; tn++) {
            bf16x8 bfr = *(const bf16x8*)(Bg + (w * 64 + tn * 16 + li) * 8);
            #pragma unroll
            for (int tm = 0; tm < 4; tm++)
                acc2[tm][tn] = __builtin_amdgcn_mfma_f32_16x16x32_bf16(afr2[tm], bfr, acc2[tm][tn], 0, 0, 0);
        }
    }

    // ---- epilogue B1: att partials (tanh * sigmoid * cW), row-reduce over features ----
    float (*apart)[8] = (float (*)[8])smem;   // [64][8] @0 (stage area dead, hh preserved)
    float sum_mr[4][4];
    #pragma unroll
    for (int a = 0; a < 4; a++)
        #pragma unroll
        for (int c = 0; c < 4; c++) sum_mr[a][c] = 0.f;
    #pragma unroll
    for (int pp = 0; pp < 2; pp++) {
        int f = w * 32 + pp * 16 + li;        // feature 0..255
        float ab_ = aab[f], bb_ = abb[f], cw = acW[f];
        #pragma unroll
        for (int tm = 0; tm < 4; tm++)
            #pragma unroll
            for (int r = 0; r < 4; r++) {
                float avv = tanhf(acc2[tm][2 * pp][r] + ab_);
                float bvv = acc2[tm][2 * pp + 1][r] + bb_;
                bvv = 1.f / (1.f + expf(-bvv));
                sum_mr[tm][r] += avv * bvv * cw;
            }
    }
    #pragma unroll
    for (int tm = 0; tm < 4; tm++)
        #pragma unroll
        for (int r = 0; r < 4; r++) {
            float v = sum_mr[tm][r];
            v += __shfl_xor(v, 1); v += __shfl_xor(v, 2);
            v += __shfl_xor(v, 4); v += __shfl_xor(v, 8);
            if (li == 0) apart[tm * 16 + q * 4 + r][w] = v;
        }

    // ---- epilogue B2: cls/inst heads = hh @ [clsW|instW]^T via VALU over LDS hh ----
    float* hpart = (float*)(smem + 2048);     // [8][64][4] f32 = 8 KB @ [2048,10240)
    {
        const int r = tid & 63, s = tid >> 6;  // s == wave id: weight loads wave-uniform
        const bf16_t* hp = hhT + r * 520 + s * 64;
        const float* w0 = clsW + s * 64;
        const float* w1 = clsW + 512 + s * 64;
        const float* w2 = instW + s * 64;
        const float* w3 = instW + 512 + s * 64;
        float h0 = 0.f, h1 = 0.f, h2 = 0.f, h3 = 0.f;
        #pragma unroll
        for (int st = 0; st < 8; st++) {
            bf16x8 hv = *(const bf16x8*)(hp + st * 8);
            #pragma unroll
            for (int j = 0; j < 8; j++) {
                float hd = (float)hv[j];
                int k = st * 8 + j;
                h0 += hd * w0[k]; h1 += hd * w1[k];
                h2 += hd * w2[k]; h3 += hd * w3[k];
            }
        }
        f32x4 hw = {h0, h1, h2, h3};
        *(f32x4*)&hpart[(s * 64 + r) * 4] = hw;
    }
    __syncthreads();

    // ---- final stores ----
    if (tid < 64) {
        float sa = acb[0];
        #pragma unroll
        for (int k = 0; k < 8; k++) sa += apart[tid][k];
        long g = row0 + tid;
        float sv = (g < NROWS) ? sa : -3e38f;
        if (g < NROWS) Araw[g] = sa;
        unsigned int key = encf(sv);
        #pragma unroll
        for (int m = 1; m < 64; m <<= 1) {
            unsigned int o = __shfl_xor(key, m);
            key = (o > key) ? o : key;
        }
        if (tid == 0) atomicMax(maxkey, key);
    } else if (tid < 320) {
        int t2 = tid - 64;
        int r = t2 >> 2, hsel = t2 & 3;
        float v = 0.f;
        #pragma unroll
        for (int s = 0; s < 8; s++) v += hpart[(s * 64 + r) * 4 + hsel];
        long g = row0 + r;
        if (g < NROWS) {
            float bias = (hsel < 2) ? clsb[hsel] : instb[hsel - 2];
            float* dst = (hsel < 2) ? inst : instLog;
            dst[g * 2 + (hsel & 1)] = v + bias;
        }
    }
}

// ---------------- merged small pass: blocks 0..7 topk partials, 8..135 softmax sums ----
__global__ void k_part(const float* __restrict__ Araw, const float* __restrict__ inst,
                       float* __restrict__ candV, int* __restrict__ candI,
                       float* __restrict__ sums) {
    __shared__ __align__(16) char sm[32768];
    int tid = threadIdx.x;        // 512
    int b = blockIdx.x;           // 0..135
    if (b < 8) {
        float* cv = (float*)sm;
        int*   ci = (int*)(sm + 16384);
        int pass = b & 1, rq = b >> 1;
        float sign = pass ? -1.f : 1.f;
        int lo = rq * 12500, hi = lo + 12500;
        float tv[8]; int ti[8];
        #pragma unroll
        for (int k = 0; k < 8; k++) { tv[k] = -1e30f; ti[k] = 0x7fffffff; }
        for (int i = lo + tid; i < hi; i += 512) {
            float v = sign * Araw[i];
            if (v > tv[7] || (v == tv[7] && i < ti[7])) {
                int k = 7;
                while (k > 0 && (v > tv[k-1] || (v == tv[k-1] && i < ti[k-1]))) {
                    tv[k] = tv[k-1]; ti[k] = ti[k-1]; k--;
                }
                tv[k] = v; ti[k] = i;
            }
        }
        #pragma unroll
        for (int k = 0; k < 8; k++) { cv[tid * 8 + k] = tv[k]; ci[tid * 8 + k] = ti[k]; }
        __syncthreads();
        if (tid < 64) {
            float mv[8]; int mi[8];
            #pragma unroll
            for (int k = 0; k < 8; k++) { mv[k] = -1e30f; mi[k] = 0x7fffffff; }
            for (int i = 0; i < 64; i++) {
                int slot = tid * 64 + ((i + tid) & 63);
                float v = cv[slot]; int idx = ci[slot];
                #pragma unroll
                for (int k = 0; k < 8; k++) {
                    bool bt = (v > mv[k]) || (v == mv[k] && idx < mi[k]);
                    float nv = bt ? v : mv[k];  int ni = bt ? idx : mi[k];
                    float ov = bt ? mv[k] : v;  int oi = bt ? mi[k] : idx;
                    mv[k] = nv; mi[k] = ni; v = ov; idx = oi;
                }
            }
            for (int r = 0; r < 8; r++) {
                float bv = mv[0]; int bi = mi[0]; int bs = tid;
                for (int m = 1; m < 64; m <<= 1) {
                    float ov = __shfl_xor(bv, m); int oi = __shfl_xor(bi, m); int os = __shfl_xor(bs, m);
                    if (ov > bv || (ov == bv && oi < bi)) { bv = ov; bi = oi; bs = os; }
                }
                if (tid == 0) {
                    candV[pass * 32 + rq * 8 + r] = bv;
                    candI[pass * 32 + rq * 8 + r] = bi;
                }
                if (tid == bs) {
                    #pragma unroll
                    for (int k = 0; k < 7; k++) { mv[k] = mv[k+1]; mi[k] = mi[k+1]; }
                    mv[7] = -1e30f; mi[7] = 0x7fffffff;
                }
            }
        }
    } else {
        float* r0 = (float*)sm;           // [8]
        float* r1 = r0 + 8;
        float* r2 = r0 + 16;
        float mx = decf(((const unsigned int*)sums)[3]);
        int i = (b - 8) * 512 + tid;
        float se = 0.f, s0 = 0.f, s1 = 0.f;
        if (i < NROWS) {
            float e = expf(Araw[i] - mx);
            se = e; s0 = inst[2 * i] * e; s1 = inst[2 * i + 1] * e;
        }
        for (int s = 1; s < 64; s <<= 1) {
            se += __shfl_xor(se, s); s0 += __shfl_xor(s0, s); s1 += __shfl_xor(s1, s);
        }
        int w = tid >> 6;
        if ((tid & 63) == 0) { r0[w] = se; r1[w] = s0; r2[w] = s1; }
        __syncthreads();
        if (tid == 0) {
            float a0 = 0.f, a1 = 0.f, a2 = 0.f;
            #pragma unroll
            for (int k = 0; k < 8; k++) { a0 += r0[k]; a1 += r1[k]; a2 += r2[k]; }
            if (a0 != 0.f || a1 != 0.f || a2 != 0.f) {
                atomicAdd(&sums[0], a0);
                atomicAdd(&sums[1], a1);
                atomicAdd(&sums[2], a2);
            }
        }
    }
}

// ---------------- finalize: merge 32+32 candidates, preds + instance_loss from logits ----
__global__ void k_fin(const float* __restrict__ instLog,
                      const float* __restrict__ candV, const int* __restrict__ candI,
                      const float* __restrict__ sums, float* __restrict__ dout) {
    __shared__ int mid[16];
    int tid = threadIdx.x;          // 128
    int wv = tid >> 6, l = tid & 63;
    if (wv < 2) {
        float v; int idx;
        if (l < 32) { v = candV[wv * 32 + l]; idx = candI[wv * 32 + l]; }
        else        { v = -1e30f; idx = 0x7fffffff; }
        for (int r = 0; r < 8; r++) {
            float bv = v; int bi = idx; int bs = l;
            for (int m = 1; m < 64; m <<= 1) {
                float ov = __shfl_xor(bv, m); int oi = __shfl_xor(bi, m); int os = __shfl_xor(bs, m);
                if (ov > bv || (ov == bv && oi < bi)) { bv = ov; bi = oi; bs = os; }
            }
            if (l == 0) mid[wv * 8 + r] = bi;
            if (l == bs) { v = -1e30f; idx = 0x7fffffff; }
        }
    }
    __syncthreads();
    if (tid < 16) {
        int id = mid[tid];
        float l0 = instLog[id * 2], l1 = instLog[id * 2 + 1];
        float mx = fmaxf(l0, l1);
        float lse = mx + logf(expf(l0 - mx) + expf(l1 - mx));
        float lt = (tid < 8) ? l1 : l0;
        float term = lse - lt;
        for (int m = 1; m < 16; m <<= 1) term += __shfl_xor(term, m);
        if (tid == 0) {
            dout[150002] = term / 16.f;
            float se = sums[0];
            dout[0] = sums[1] / se;
            dout[1] = sums[2] / se;
        }
    }
}

extern "C" void kernel_launch(void* const* d_in, const int* in_sizes, int n_in,
                              void* d_out, int out_size, void* d_ws, size_t ws_size,
                              hipStream_t stream) {
    const float* h   = (const float*)d_in[0];
    const float* fcW = (const float*)d_in[1];
    const float* fcb = (const float*)d_in[2];
    const float* aaW = (const float*)d_in[3];
    const float* aab = (const float*)d_in[4];
    const float* abW = (const float*)d_in[5];
    const float* abb = (const float*)d_in[6];
    const float* acW = (const float*)d_in[7];
    const float* acb = (const float*)d_in[8];
    const float* clW = (const float*)d_in[9];
    const float* clb = (const float*)d_in[10];
    const float* inW = (const float*)d_in[11];
    const float* inb = (const float*)d_in[12];
    float* out = (float*)d_out;

    char* ws = (char*)d_ws;
    bf16_t* permW1  = (bf16_t*)(ws);                       // 1,048,576 B
    bf16_t* permB2  = (bf16_t*)(ws + 1048576);             // 524,288 B
    float*  instLog = (float*) (ws + 1572864);             // 400,000 B
    float*  candV   = (float*) (ws + 1972864);             // 256 B
    int*    candI   = (int*)   (ws + 1973120);             // 256 B
    float*  sums    = (float*) (ws + 1973376);             // 16 B (s0,s1,s2,maxkey)

    float* inst = out + 2;
    float* Araw = out + 2 + 100000;

    k_convert<<<768, 256, 0, stream>>>(fcW, aaW, abW, permW1, permB2, sums);
    k_fused<<<782, 512, 0, stream>>>(h, permW1, permB2, fcb, aab, abb, acW, acb,
                                     clW, clb, inW, inb,
                                     Araw, inst, instLog, (unsigned int*)sums + 3);
    k_part<<<136, 512, 0, stream>>>(Araw, inst, candV, candI, sums);
    k_fin<<<1, 128, 0, stream>>>(instLog, candV, candI, sums, out);
}

// Round 5
// 453.133 us; speedup vs baseline: 1.2983x; 1.0263x over previous
//
#include <hip/hip_runtime.h>
#include <hip/hip_bf16.h>
#include <math.h>

typedef __bf16 bf16_t;
typedef __bf16 bf16x4 __attribute__((ext_vector_type(4)));
typedef __bf16 bf16x8 __attribute__((ext_vector_type(8)));
typedef float  f32x4  __attribute__((ext_vector_type(4)));

#define NROWS 50000

// monotone float<->uint mapping for atomicMax on floats
__device__ __forceinline__ unsigned int encf(float f) {
    unsigned int u = __float_as_uint(f);
    return (u >> 31) ? ~u : (u | 0x80000000u);
}
__device__ __forceinline__ float decf(unsigned int u) {
    return (u >> 31) ? __uint_as_float(u & 0x7fffffffu) : __uint_as_float(~u);
}

// ---------------- weight permutation ----------------
// permW1[kt 0..31][q 0..3][row 0..511][8] = fcW[row][kt*32+q*8+j]
// permB2[kt 0..15][q 0..3][r 0..511][8]   = interleaved a/b rows
__global__ void k_convert(const float* __restrict__ fcW,
                          const float* __restrict__ aW,
                          const float* __restrict__ bW,
                          bf16_t* __restrict__ permW1, bf16_t* __restrict__ permB2,
                          float* __restrict__ sums) {
    int t = blockIdx.x * 256 + threadIdx.x;
    if (t == 0) {
        sums[0] = 0.f; sums[1] = 0.f; sums[2] = 0.f;
        ((unsigned int*)sums)[3] = 0u;          // maxkey = encf(most negative)
    }
    if (t < 131072) {
        float4 v = *(const float4*)(fcW + (long)t * 4);
        int row = t >> 8;
        int k0 = (t & 255) * 4;
        int kt = k0 >> 5, q = (k0 >> 3) & 3, j = k0 & 7;
        bf16_t o[4] = {(bf16_t)v.x, (bf16_t)v.y, (bf16_t)v.z, (bf16_t)v.w};
        *(bf16x4*)(permW1 + kt * 16384 + q * 4096 + row * 8 + j) = *(bf16x4*)o;
    } else if (t < 196608) {
        int t2 = t - 131072;
        int isB = t2 >> 15;
        int f = t2 & 32767;
        float4 v = *(const float4*)(((isB ? bW : aW)) + (long)f * 4);
        int srow = f >> 7;
        int k0 = (f & 127) * 4;
        int kt = k0 >> 5, q = (k0 >> 3) & 3, j = k0 & 7;
        int r = ((srow >> 4) * 2 + isB) * 16 + (srow & 15);
        bf16_t o[4] = {(bf16_t)v.x, (bf16_t)v.y, (bf16_t)v.z, (bf16_t)v.w};
        *(bf16x4*)(permB2 + kt * 16384 + q * 4096 + r * 8 + j) = *(bf16x4*)o;
    }
}

// ---------------- fused: GEMM1 -> hh in LDS -> GEMM2 + att + cls/inst heads ----
// 512 threads = 8 waves, 1x8 layout (wave w owns all 64 rows x cols [w*64, w*64+64)).
// x loads are NONTEMPORAL (nt): x is 205 MB single-use streaming data; keeping it out
// of L1/L2 leaves the 1.5 MB hot weight set (permW1/permB2) cache-resident so the
// per-kt weight fragment loads run at L2 latency instead of L3.
// LDS 76.8 KB -> 2 blocks/CU, 4 waves/SIMD. Regs: 64 AGPR acc + 64 arch = 128 cap.
__global__ __launch_bounds__(512, 4) void k_fused(
        const float* __restrict__ x,
        const bf16_t* __restrict__ permW1, const bf16_t* __restrict__ permB2,
        const float* __restrict__ fcb,
        const float* __restrict__ aab, const float* __restrict__ abb,
        const float* __restrict__ acW, const float* __restrict__ acb,
        const float* __restrict__ clsW, const float* __restrict__ clsb,
        const float* __restrict__ instW, const float* __restrict__ instb,
        float* __restrict__ Araw, float* __restrict__ inst,
        float* __restrict__ instLog, unsigned int* __restrict__ maxkey) {
    __shared__ __align__(16) char smem[76800];
    // [0,10240): x-stage dbuf 2 x [64 rows][40 elems] bf16 (row stride 80 B)
    // [10240,76800): hhT [64][520] bf16 (row stride 1040 B, 2-way banks on b128 col reads)
    bf16_t* hhT = (bf16_t*)(smem + 10240);

    const int tid = threadIdx.x;
    const int w = tid >> 6, l = tid & 63, q = l >> 4, li = l & 15;
    const long row0 = (long)blockIdx.x * 64;

    // ================= phase A: hh = relu(x @ W1^T + fcb) =================
    f32x4 acc[4][4];
    #pragma unroll
    for (int a = 0; a < 4; a++)
        #pragma unroll
        for (int c = 0; c < 4; c++) acc[a][c] = (f32x4)0.0f;

    const int srow = tid >> 3;            // 0..63
    const int sk   = (tid & 7) * 4;       // 0,4,..,28
    const bool av  = (row0 + srow) < NROWS;
    const float* xr = x + (row0 + srow) * 1024 + sk;

    f32x4 xv = av ? __builtin_nontemporal_load((const f32x4*)xr) : (f32x4)0.0f;
    {
        bf16_t o[4] = {(bf16_t)xv[0], (bf16_t)xv[1], (bf16_t)xv[2], (bf16_t)xv[3]};
        *(bf16x4*)(smem + srow * 80 + sk * 2) = *(bf16x4*)o;
    }
    xv = av ? __builtin_nontemporal_load((const f32x4*)(xr + 32)) : (f32x4)0.0f;
    __syncthreads();

    for (int kt = 0; kt < 32; kt++) {
        const int cur = kt & 1;
        if (kt < 31) {
            bf16_t o[4] = {(bf16_t)xv[0], (bf16_t)xv[1], (bf16_t)xv[2], (bf16_t)xv[3]};
            *(bf16x4*)(smem + (cur ^ 1) * 5120 + srow * 80 + sk * 2) = *(bf16x4*)o;
            if (kt < 30)
                xv = av ? __builtin_nontemporal_load((const f32x4*)(xr + (kt + 2) * 32))
                        : (f32x4)0.0f;
        }
        const char* As = smem + cur * 5120;
        const bf16_t* Bg = permW1 + kt * 16384 + q * 4096;
        bf16x8 afr[4];
        #pragma unroll
        for (int tm = 0; tm < 4; tm++)
            afr[tm] = *(const bf16x8*)(As + (tm * 16 + li) * 80 + q * 16);
        #pragma unroll
        for (int tn = 0; tn < 4; tn++) {
            bf16x8 bfr = *(const bf16x8*)(Bg + (w * 64 + tn * 16 + li) * 8);
            #pragma unroll
            for (int tm = 0; tm < 4; tm++)
                acc[tm][tn] = __builtin_amdgcn_mfma_f32_16x16x32_bf16(afr[tm], bfr, acc[tm][tn], 0, 0, 0);
        }
        __syncthreads();
    }

    // ---- epilogue A: bias + relu, write hh tile to LDS ----
    #pragma unroll
    for (int tn = 0; tn < 4; tn++) {
        float bias = fcb[w * 64 + tn * 16 + li];
        #pragma unroll
        for (int tm = 0; tm < 4; tm++)
            #pragma unroll
            for (int r = 0; r < 4; r++) {
                float v = acc[tm][tn][r] + bias;
                v = v > 0.f ? v : 0.f;
                hhT[(tm * 16 + q * 4 + r) * 520 + w * 64 + tn * 16 + li] = (bf16_t)v;
            }
    }
    __syncthreads();

    // ================= phase B: [a|b] = hh @ W2^T, barrier-free =================
    f32x4 acc2[4][4];
    #pragma unroll
    for (int a = 0; a < 4; a++)
        #pragma unroll
        for (int c = 0; c < 4; c++) acc2[a][c] = (f32x4)0.0f;

    for (int kt = 0; kt < 16; kt++) {
        const bf16_t* Bg = permB2 + kt * 16384 + q * 4096;
        bf16x8 afr2[4];
        #pragma unroll
        for (int tm = 0; tm < 4; tm++)
            afr2[tm] = *(const bf16x8*)(hhT + (tm * 16 + li) * 520 + kt * 32 + q * 8);
        #pragma unroll
        for (int tn = 0; tn < 4; tn++) {
            bf16x8 bfr = *(const bf16x8*)(Bg + (w * 64 + tn * 16 + li) * 8);
            #pragma unroll
            for (int tm = 0; tm < 4; tm++)
                acc2[tm][tn] = __builtin_amdgcn_mfma_f32_16x16x32_bf16(afr2[tm], bfr, acc2[tm][tn], 0, 0, 0);
        }
    }

    // ---- epilogue B1: att partials (tanh * sigmoid * cW), row-reduce over features ----
    float (*apart)[8] = (float (*)[8])smem;   // [64][8] @0 (stage area dead, hh preserved)
    float sum_mr[4][4];
    #pragma unroll
    for (int a = 0; a < 4; a++)
        #pragma unroll
        for (int c = 0; c < 4; c++) sum_mr[a][c] = 0.f;
    #pragma unroll
    for (int pp = 0; pp < 2; pp++) {
        int f = w * 32 + pp * 16 + li;        // feature 0..255
        float ab_ = aab[f], bb_ = abb[f], cw = acW[f];
        #pragma unroll
        for (int tm = 0; tm < 4; tm++)
            #pragma unroll
            for (int r = 0; r < 4; r++) {
                float avv = tanhf(acc2[tm][2 * pp][r] + ab_);
                float bvv = acc2[tm][2 * pp + 1][r] + bb_;
                bvv = 1.f / (1.f + expf(-bvv));
                sum_mr[tm][r] += avv * bvv * cw;
            }
    }
    #pragma unroll
    for (int tm = 0; tm < 4; tm++)
        #pragma unroll
        for (int r = 0; r < 4; r++) {
            float v = sum_mr[tm][r];
            v += __shfl_xor(v, 1); v += __shfl_xor(v, 2);
            v += __shfl_xor(v, 4); v += __shfl_xor(v, 8);
            if (li == 0) apart[tm * 16 + q * 4 + r][w] = v;
        }

    // ---- epilogue B2: cls/inst heads = hh @ [clsW|instW]^T via VALU over LDS hh ----
    float* hpart = (float*)(smem + 2048);     // [8][64][4] f32 = 8 KB @ [2048,10240)
    {
        const int r = tid & 63, s = tid >> 6;  // s == wave id: weight loads wave-uniform
        const bf16_t* hp = hhT + r * 520 + s * 64;
        const float* w0 = clsW + s * 64;
        const float* w1 = clsW + 512 + s * 64;
        const float* w2 = instW + s * 64;
        const float* w3 = instW + 512 + s * 64;
        float h0 = 0.f, h1 = 0.f, h2 = 0.f, h3 = 0.f;
        #pragma unroll
        for (int st = 0; st < 8; st++) {
            bf16x8 hv = *(const bf16x8*)(hp + st * 8);
            #pragma unroll
            for (int j = 0; j < 8; j++) {
                float hd = (float)hv[j];
                int k = st * 8 + j;
                h0 += hd * w0[k]; h1 += hd * w1[k];
                h2 += hd * w2[k]; h3 += hd * w3[k];
            }
        }
        f32x4 hw = {h0, h1, h2, h3};
        *(f32x4*)&hpart[(s * 64 + r) * 4] = hw;
    }
    __syncthreads();

    // ---- final stores ----
    if (tid < 64) {
        float sa = acb[0];
        #pragma unroll
        for (int k = 0; k < 8; k++) sa += apart[tid][k];
        long g = row0 + tid;
        float sv = (g < NROWS) ? sa : -3e38f;
        if (g < NROWS) Araw[g] = sa;
        unsigned int key = encf(sv);
        #pragma unroll
        for (int m = 1; m < 64; m <<= 1) {
            unsigned int o = __shfl_xor(key, m);
            key = (o > key) ? o : key;
        }
        if (tid == 0) atomicMax(maxkey, key);
    } else if (tid < 320) {
        int t2 = tid - 64;
        int r = t2 >> 2, hsel = t2 & 3;
        float v = 0.f;
        #pragma unroll
        for (int s = 0; s < 8; s++) v += hpart[(s * 64 + r) * 4 + hsel];
        long g = row0 + r;
        if (g < NROWS) {
            float bias = (hsel < 2) ? clsb[hsel] : instb[hsel - 2];
            float* dst = (hsel < 2) ? inst : instLog;
            dst[g * 2 + (hsel & 1)] = v + bias;
        }
    }
}

// ---------------- merged small pass: blocks 0..7 topk partials, 8..135 softmax sums ----
__global__ void k_part(const float* __restrict__ Araw, const float* __restrict__ inst,
                       float* __restrict__ candV, int* __restrict__ candI,
                       float* __restrict__ sums) {
    __shared__ __align__(16) char sm[32768];
    int tid = threadIdx.x;        // 512
    int b = blockIdx.x;           // 0..135
    if (b < 8) {
        float* cv = (float*)sm;
        int*   ci = (int*)(sm + 16384);
        int pass = b & 1, rq = b >> 1;
        float sign = pass ? -1.f : 1.f;
        int lo = rq * 12500, hi = lo + 12500;
        float tv[8]; int ti[8];
        #pragma unroll
        for (int k = 0; k < 8; k++) { tv[k] = -1e30f; ti[k] = 0x7fffffff; }
        for (int i = lo + tid; i < hi; i += 512) {
            float v = sign * Araw[i];
            if (v > tv[7] || (v == tv[7] && i < ti[7])) {
                int k = 7;
                while (k > 0 && (v > tv[k-1] || (v == tv[k-1] && i < ti[k-1]))) {
                    tv[k] = tv[k-1]; ti[k] = ti[k-1]; k--;
                }
                tv[k] = v; ti[k] = i;
            }
        }
        #pragma unroll
        for (int k = 0; k < 8; k++) { cv[tid * 8 + k] = tv[k]; ci[tid * 8 + k] = ti[k]; }
        __syncthreads();
        if (tid < 64) {
            float mv[8]; int mi[8];
            #pragma unroll
            for (int k = 0; k < 8; k++) { mv[k] = -1e30f; mi[k] = 0x7fffffff; }
            for (int i = 0; i < 64; i++) {
                int slot = tid * 64 + ((i + tid) & 63);
                float v = cv[slot]; int idx = ci[slot];
                #pragma unroll
                for (int k = 0; k < 8; k++) {
                    bool bt = (v > mv[k]) || (v == mv[k] && idx < mi[k]);
                    float nv = bt ? v : mv[k];  int ni = bt ? idx : mi[k];
                    float ov = bt ? mv[k] : v;  int oi = bt ? mi[k] : idx;
                    mv[k] = nv; mi[k] = ni; v = ov; idx = oi;
                }
            }
            for (int r = 0; r < 8; r++) {
                float bv = mv[0]; int bi = mi[0]; int bs = tid;
                for (int m = 1; m < 64; m <<= 1) {
                    float ov = __shfl_xor(bv, m); int oi = __shfl_xor(bi, m); int os = __shfl_xor(bs, m);
                    if (ov > bv || (ov == bv && oi < bi)) { bv = ov; bi = oi; bs = os; }
                }
                if (tid == 0) {
                    candV[pass * 32 + rq * 8 + r] = bv;
                    candI[pass * 32 + rq * 8 + r] = bi;
                }
                if (tid == bs) {
                    #pragma unroll
                    for (int k = 0; k < 7; k++) { mv[k] = mv[k+1]; mi[k] = mi[k+1]; }
                    mv[7] = -1e30f; mi[7] = 0x7fffffff;
                }
            }
        }
    } else {
        float* r0 = (float*)sm;           // [8]
        float* r1 = r0 + 8;
        float* r2 = r0 + 16;
        float mx = decf(((const unsigned int*)sums)[3]);
        int i = (b - 8) * 512 + tid;
        float se = 0.f, s0 = 0.f, s1 = 0.f;
        if (i < NROWS) {
            float e = expf(Araw[i] - mx);
            se = e; s0 = inst[2 * i] * e; s1 = inst[2 * i + 1] * e;
        }
        for (int s = 1; s < 64; s <<= 1) {
            se += __shfl_xor(se, s); s0 += __shfl_xor(s0, s); s1 += __shfl_xor(s1, s);
        }
        int w = tid >> 6;
        if ((tid & 63) == 0) { r0[w] = se; r1[w] = s0; r2[w] = s1; }
        __syncthreads();
        if (tid == 0) {
            float a0 = 0.f, a1 = 0.f, a2 = 0.f;
            #pragma unroll
            for (int k = 0; k < 8; k++) { a0 += r0[k]; a1 += r1[k]; a2 += r2[k]; }
            if (a0 != 0.f || a1 != 0.f || a2 != 0.f) {
                atomicAdd(&sums[0], a0);
                atomicAdd(&sums[1], a1);
                atomicAdd(&sums[2], a2);
            }
        }
    }
}

// ---------------- finalize: merge 32+32 candidates, preds + instance_loss from logits ----
__global__ void k_fin(const float* __restrict__ instLog,
                      const float* __restrict__ candV, const int* __restrict__ candI,
                      const float* __restrict__ sums, float* __restrict__ dout) {
    __shared__ int mid[16];
    int tid = threadIdx.x;          // 128
    int wv = tid >> 6, l = tid & 63;
    if (wv < 2) {
        float v; int idx;
        if (l < 32) { v = candV[wv * 32 + l]; idx = candI[wv * 32 + l]; }
        else        { v = -1e30f; idx = 0x7fffffff; }
        for (int r = 0; r < 8; r++) {
            float bv = v; int bi = idx; int bs = l;
            for (int m = 1; m < 64; m <<= 1) {
                float ov = __shfl_xor(bv, m); int oi = __shfl_xor(bi, m); int os = __shfl_xor(bs, m);
                if (ov > bv || (ov == bv && oi < bi)) { bv = ov; bi = oi; bs = os; }
            }
            if (l == 0) mid[wv * 8 + r] = bi;
            if (l == bs) { v = -1e30f; idx = 0x7fffffff; }
        }
    }
    __syncthreads();
    if (tid < 16) {
        int id = mid[tid];
        float l0 = instLog[id * 2], l1 = instLog[id * 2 + 1];
        float mx = fmaxf(l0, l1);
        float lse = mx + logf(expf(l0 - mx) + expf(l1 - mx));
        float lt = (tid < 8) ? l1 : l0;
        float term = lse - lt;
        for (int m = 1; m < 16; m <<= 1) term += __shfl_xor(term, m);
        if (tid == 0) {
            dout[150002] = term / 16.f;
            float se = sums[0];
            dout[0] = sums[1] / se;
            dout[1] = sums[2] / se;
        }
    }
}

extern "C" void kernel_launch(void* const* d_in, const int* in_sizes, int n_in,
                              void* d_out, int out_size, void* d_ws, size_t ws_size,
                              hipStream_t stream) {
    const float* h   = (const float*)d_in[0];
    const float* fcW = (const float*)d_in[1];
    const float* fcb = (const float*)d_in[2];
    const float* aaW = (const float*)d_in[3];
    const float* aab = (const float*)d_in[4];
    const float* abW = (const float*)d_in[5];
    const float* abb = (const float*)d_in[6];
    const float* acW = (const float*)d_in[7];
    const float* acb = (const float*)d_in[8];
    const float* clW = (const float*)d_in[9];
    const float* clb = (const float*)d_in[10];
    const float* inW = (const float*)d_in[11];
    const float* inb = (const float*)d_in[12];
    float* out = (float*)d_out;

    char* ws = (char*)d_ws;
    bf16_t* permW1  = (bf16_t*)(ws);                       // 1,048,576 B
    bf16_t* permB2  = (bf16_t*)(ws + 1048576);             // 524,288 B
    float*  instLog = (float*) (ws + 1572864);             // 400,000 B
    float*  candV   = (float*) (ws + 1972864);             // 256 B
    int*    candI   = (int*)   (ws + 1973120);             // 256 B
    float*  sums    = (float*) (ws + 1973376);             // 16 B (s0,s1,s2,maxkey)

    float* inst = out + 2;
    float* Araw = out + 2 + 100000;

    k_convert<<<768, 256, 0, stream>>>(fcW, aaW, abW, permW1, permB2, sums);
    k_fused<<<782, 512, 0, stream>>>(h, permW1, permB2, fcb, aab, abb, acW, acb,
                                     clW, clb, inW, inb,
                                     Araw, inst, instLog, (unsigned int*)sums + 3);
    k_part<<<136, 512, 0, stream>>>(Araw, inst, candV, candI, sums);
    k_fin<<<1, 128, 0, stream>>>(instLog, candV, candI, sums, out);
}